// Round 21
// baseline (412.017 us; speedup 1.0000x reference)
//
#include <hip/hip_runtime.h>

typedef __attribute__((ext_vector_type(8)))  _Float16 f16x8; // 8 f16 = 4 VGPR MFMA operand
typedef __attribute__((ext_vector_type(16))) float f32x16;   // 32x32 MFMA accumulator

#define XIM (32*256*256)
#define MAXFIX 65536

__device__ __forceinline__ short f2h(float f){
    _Float16 h = (_Float16)f;                  // v_cvt_f16_f32, RNE
    return __builtin_bit_cast(short, h);
}
__device__ __forceinline__ void glds16(const short* g, short* l){
    __builtin_amdgcn_global_load_lds(
        (const __attribute__((address_space(1))) unsigned int*)g,
        (__attribute__((address_space(3))) unsigned int*)l,
        16, 0, 0);
}

// ---- prep: folded expert weights W'_e=W_e+W_s -> f16 wt2[es8][tap9][cio4][cout32][8ci] (144KB);
//      biasmat[c32][k16]; gate weights f16 gwA[tap9][cio4][row32][8ci] (rows 8..31 zero);
//      cnt=cnt2=0. ----
__global__ __launch_bounds__(256) void prep_weights(const float* __restrict__ ew,
                                                    const float* __restrict__ sw,
                                                    const float* __restrict__ ebv,
                                                    const float* __restrict__ sbv,
                                                    const float* __restrict__ gw,
                                                    short* __restrict__ wt2,
                                                    short* __restrict__ gwA,
                                                    int* __restrict__ cnt){
    int i = blockIdx.x * 256 + threadIdx.x;      // 326 blocks * 256 = 83456 exactly
    if(i < 2) cnt[i] = 0;
    if(i < 73728){
        int c7  = i & 7;
        int col = (i >> 3) & 31;                 // cout
        int cio = (i >> 8) & 3;                  // ci octet
        int rest = i >> 10;                      // 0..71
        int tap = rest % 9;
        int es  = rest / 9;                      // 0..7
        int ci  = cio*8 + c7;
        float v = ew[((es*32 + col)*32 + ci)*9 + tap] + sw[(col*32 + ci)*9 + tap];
        wt2[i] = f2h(v);
    } else if(i < 74240){                        // biasmat: k<8 -> eb+sb, else 0
        int j = i - 73728, c = j >> 4, k = j & 15;
        float v = (k < 8) ? (ebv[k*32 + c] + sbv[c]) : 0.f;
        wt2[i] = f2h(v);
    } else {                                     // gwA (single f16 copy)
        int i2 = i - 74240;                      // 0..9215
        int c7  = i2 & 7;
        int row = (i2 >> 3) & 31;
        int cio = (i2 >> 8) & 3;
        int tap = i2 >> 10;                      // 0..8
        float v = (row < 8) ? gw[row*288 + (cio*8 + c7)*9 + tap] : 0.f;
        gwA[i2] = f2h(v);
    }
}

// ---- fused main: weights-stationary moe + in-kernel f16 gate MFMA + top2/softmax.
//      Flag compaction: LDS staging + ONE global atomic per block (kills L2 RMW serialization).
//      2048 blocks x 512 thr; 8 waves x 1 row; 144K+10.9K+1K LDS; VGPR<=128. ----
__global__ __launch_bounds__(512, 2) void moe_main(const float* __restrict__ x,
                                                   const short* __restrict__ wt2,
                                                   const short* __restrict__ gwA,
                                                   const float* __restrict__ gb,
                                                   float* __restrict__ out,
                                                   int* __restrict__ cnt,
                                                   int* __restrict__ fixlist){
    __shared__ __align__(16) short wlds[73728];      // [es8][tap9][cio4][cout32][8ci], 144 KB
    __shared__ __align__(16) short xt[10*2*34*8];    // [row10][cic2][px34][8ci] one hf, 10.88 KB
    __shared__ int fstage[256];                      // flagged-pixel staging (<=256/block)
    __shared__ int fcnt, fbase;
    int raw = blockIdx.x;                            // 2048; XCD chunk swizzle
    int wg  = (raw & 7)*256 + (raw >> 3);
    int b   = wg >> 8;
    int y0  = ((wg >> 3) & 31) * 8;
    int x0  = (wg & 7) * 32;
    int t   = threadIdx.x;                           // 0..511
    int wv  = t >> 6, l = t & 63, col = l & 31, hi = l >> 5;
    if(t == 0) fcnt = 0;

    // stage ALL folded weights once: 144 chunks of 1 KB over 8 waves, async
    #pragma unroll
    for(int j=0;j<18;++j){
        int c = wv + 8*j;
        glds16(wt2 + c*512 + l*8, wlds + c*512);
    }

    const float* xim = x + (size_t)b*XIM;
    int yy = y0 + wv;                                // this wave's output row
    f16x8 biasA = *(const f16x8*)(wt2 + 73728 + col*16 + hi*8);        // L2-hot

    // x tile: stage per ci-half into xt (b128-packed f16), cache B-frags in regs
    f16x8 Bf[3][2][3];                               // [kh][hf][kw] = 72 VGPR
    #pragma unroll
    for(int hf=0; hf<2; ++hf){
        if(hf) __syncthreads();                      // hf0 Bf reads done before overwrite
        #pragma unroll
        for(int i=0;i<2;++i){
            int u = t + i*512;                       // 640 main units: [row10][cic2][px32]
            if(u < 640){
                int px = u & 31, rc = u >> 5;        // rc 0..19 = row*2+cic
                int row = rc >> 1, cic = rc & 1;
                int cib = hf*16 + cic*8;
                int ry = y0 - 1 + row, xx = x0 - 1 + px;
                bool ok = (ry>=0 && ry<256 && xx>=0 && xx<256);
                f16x8 pk;
                #pragma unroll
                for(int j2=0;j2<8;++j2){
                    float v = ok ? xim[((size_t)(cib+j2)*256 + ry)*256 + xx] : 0.f;
                    pk[j2] = (_Float16)v;
                }
                *(f16x8*)(&xt[((row*2 + cic)*34 + px)*8]) = pk;
            }
        }
        if(t < 40){                                  // halo units: px 32,33
            int pxh = 32 + (t & 1), rc = t >> 1;     // rc 0..19
            int row = rc >> 1, cic = rc & 1;
            int cib = hf*16 + cic*8;
            int ry = y0 - 1 + row, xx = x0 - 1 + pxh;
            bool ok = (ry>=0 && ry<256 && xx>=0 && xx<256);
            f16x8 pk;
            #pragma unroll
            for(int j2=0;j2<8;++j2){
                float v = ok ? xim[((size_t)(cib+j2)*256 + ry)*256 + xx] : 0.f;
                pk[j2] = (_Float16)v;
            }
            *(f16x8*)(&xt[((row*2 + cic)*34 + pxh)*8]) = pk;
        }
        __syncthreads();                             // xt(hf) staged; 1st also drains weight glds
        #pragma unroll
        for(int kh=0;kh<3;++kh)                      // wave rows wv..wv+2
            #pragma unroll
            for(int kw=0;kw<3;++kw)
                Bf[kh][hf][kw] = *(const f16x8*)(&xt[(((wv+kh)*2 + hi)*34 + col + kw)*8]);
    }

    // ---- fused gate: single-pass f16 MFMA; rows 0..7 = experts ----
    f32x16 ga = {};
    #pragma unroll
    for(int tap=0; tap<9; ++tap){
        const int kh = tap/3, kw = tap - kh*3;
        #pragma unroll
        for(int hf=0; hf<2; ++hf){
            f16x8 a = *(const f16x8*)(gwA + ((tap*4 + hf*2 + hi)*32 + col)*8);
            ga = __builtin_amdgcn_mfma_f32_32x32x16_f16(a, Bf[kh][hf][kw], ga, 0,0,0);
        }
    }
    // lane (col,hi) holds expert rows 4hi..4hi+3 in ga[0..3]; swap with partner (hi^1)
    float gsc[8];
    #pragma unroll
    for(int j=0;j<4;++j){
        float own = ga[j];
        float prt = __shfl_xor(own, 32);
        gsc[j]   = hi ? prt : own;
        gsc[4+j] = hi ? own : prt;
    }
    float v1b=-1e30f, v2b=-1e30f, v3b=-1e30f, r1=0.f, r2=0.f; int i1=-1, i2=-1;
    #pragma unroll
    for(int e=0;e<8;e++){
        float se = 1.f/(1.f + expf(-gsc[e]));
        float be = se + gb[e];
        if(be > v1b){ v3b=v2b; v2b=v1b; r2=r1; i2=i1; v1b=be; r1=se; i1=e; }
        else if(be > v2b){ v3b=v2b; v2b=be; r2=se; i2=e; }
        else if(be > v3b){ v3b=be; }
    }
    if(hi == 0 && (v2b - v3b < 3e-4f)){              // margin guard -> LDS staging (fast atomic)
        int s = atomicAdd(&fcnt, 1);
        fstage[s] = (b << 22) | (yy << 14) | ((x0 + col) << 6) | (i1 << 3) | i2;
    }
    float m  = fmaxf(r1, r2);
    float e1 = expf(r1-m), e2 = expf(r2-m);
    float inv = 1.f/(e1+e2);
    float w1 = e1*inv, w2 = e2*inv;                  // ROUTE_SCALE = 1
    f16x8 rfrag;
    #pragma unroll
    for(int e=0;e<8;e++){
        float dv = (e==i1) ? w1 : ((e==i2) ? w2 : 0.f);
        rfrag[e] = (_Float16)dv;
    }

    f32x16 z = {};
    f32x16 oa = __builtin_amdgcn_mfma_f32_32x32x16_f16(biasA, rfrag, z, 0,0,0);

    #pragma unroll
    for(int es=0; es<8; ++es){                       // folded experts (shared absorbed)
        f32x16 acc = {};
        #pragma unroll
        for(int tap=0; tap<9; ++tap){
            const int kh = tap/3, kw = tap - kh*3;
            #pragma unroll
            for(int hf=0; hf<2; ++hf){
                f16x8 a = *(const f16x8*)(&wlds[(((es*9 + tap)*4 + hf*2 + hi)*32 + col)*8]);
                acc = __builtin_amdgcn_mfma_f32_32x32x16_f16(a, Bf[kh][hf][kw], acc, 0,0,0);
            }
        }
        float d = (es==i1) ? w1 : ((es==i2) ? w2 : 0.f);
        #pragma unroll
        for(int r=0;r<16;r++) oa[r] += d*acc[r];
    }

    float* ob = out + (size_t)b*XIM;
    #pragma unroll
    for(int r=0;r<16;r++){
        int c = hi*4 + (r&3) + 8*(r>>2);             // C/D: col=lane&31, row=(r&3)+8*(r>>2)+4*hi
        ob[((size_t)c*256 + yy)*256 + x0 + col] = oa[r];
    }

    // ---- flush flags: ONE global atomic per block reserves a fixlist range ----
    __syncthreads();                                 // all LDS flag-writes done
    if(t == 0 && fcnt > 0) fbase = atomicAdd(cnt, fcnt);
    __syncthreads();
    if(t < fcnt){
        int dst = fbase + t;
        if(dst < MAXFIX) fixlist[dst] = fstage[t];
    }
}

// ---- fixup A: fp64 gate re-selection; emit repair job ONLY if selection set changed ----
__global__ __launch_bounds__(256) void fixup_route(const float* __restrict__ x,
                                                   const float* __restrict__ gw,
                                                   const float* __restrict__ gb,
                                                   int* __restrict__ cnt,        // [0]=n, [1]=n2
                                                   const int* __restrict__ fixlist,
                                                   int4* __restrict__ fxroute){
    int n = cnt[0]; if(n > MAXFIX) n = MAXFIX;
    int idx = blockIdx.x*256 + threadIdx.x;          // grid covers MAXFIX exactly
    if(idx >= n) return;
    int pk = fixlist[idx];
    int b  = pk >> 22, y = (pk >> 14) & 255, xx = (pk >> 6) & 255;
    int mi1 = (pk >> 3) & 7, mi2 = pk & 7;
    const float* xim = x + (size_t)b*XIM;
    double gd[8];
    #pragma unroll
    for(int e=0;e<8;e++) gd[e] = 0.0;
    for(int ci=0; ci<32; ++ci){
        for(int kh=0; kh<3; ++kh){
            int yy2 = y + kh - 1;
            if(yy2 < 0 || yy2 >= 256) continue;
            const float* xr = xim + ((size_t)ci*256 + yy2)*256;
            for(int kw=0; kw<3; ++kw){
                int xc = xx + kw - 1;
                if(xc < 0 || xc >= 256) continue;
                double xv = (double)xr[xc];
                #pragma unroll
                for(int e=0;e<8;e++) gd[e] += xv * (double)gw[e*288 + ci*9 + kh*3 + kw];
            }
        }
    }
    double b1=-1e30, b2=-1e30; double rr1=0.0, rr2=0.0; int j1=-1, j2=-1;
    #pragma unroll
    for(int e=0;e<8;e++){
        double sd = 1.0/(1.0 + exp(-gd[e]));
        double bd = sd + (double)gb[e];
        if(bd > b1){ b2=b1; rr2=rr1; j2=j1; b1=bd; rr1=sd; j1=e; }
        else if(bd > b2){ b2=bd; rr2=sd; j2=e; }
    }
    bool same = (j1==mi1 && j2==mi2) || (j1==mi2 && j2==mi1);   // set equality -> skip
    if(same) return;
    float r1 = (float)rr1, r2 = (float)rr2;
    float m  = fmaxf(r1, r2);
    float e1 = expf(r1-m), e2 = expf(r2-m);
    float inv = 1.f/(e1+e2);
    int slot = atomicAdd(cnt+1, 1);
    fxroute[slot] = make_int4((b<<16)|(y<<8)|xx, (j1<<3)|j2,
                              __float_as_int(e1*inv), __float_as_int(e2*inv));
}

// ---- fixup B: exact fp32 output rewrite for re-routed pixels (tiny list) ----
__global__ __launch_bounds__(256) void fixup_out(const float* __restrict__ x,
                                                 const float* __restrict__ ew,
                                                 const float* __restrict__ sw,
                                                 const float* __restrict__ ebv,
                                                 const float* __restrict__ sbv,
                                                 const int* __restrict__ cnt,
                                                 const int4* __restrict__ fxroute,
                                                 float* __restrict__ out){
    int n2 = cnt[1];
    int total = n2 * 32;
    for(int u = blockIdx.x*256 + threadIdx.x; u < total; u += 128*256){
        int idx = u >> 5, c = u & 31;
        int4 fr = fxroute[idx];
        int pix = fr.x;
        int b  = pix >> 16, y = (pix >> 8) & 255, xx = pix & 255;
        int i1 = (fr.y >> 3) & 7, i2 = fr.y & 7;
        float w1 = __int_as_float(fr.z), w2 = __int_as_float(fr.w);
        float acc = w1*ebv[i1*32 + c] + w2*ebv[i2*32 + c] + sbv[c];   // w1+w2=1 absorbs sb
        const float* xim = x + (size_t)b*XIM;
        const float* e1w = ew + ((size_t)(i1*32 + c))*288;            // [ci][kh][kw]
        const float* e2w = ew + ((size_t)(i2*32 + c))*288;
        const float* shw = sw + (size_t)c*288;
        for(int ci=0; ci<32; ++ci){
            for(int kh=0; kh<3; ++kh){
                int yy = y + kh - 1;
                if(yy < 0 || yy >= 256) continue;
                const float* xr = xim + ((size_t)ci*256 + yy)*256;
                for(int kw=0; kw<3; ++kw){
                    int xc = xx + kw - 1;
                    if(xc < 0 || xc >= 256) continue;
                    int wi = ci*9 + kh*3 + kw;
                    float wv = w1*e1w[wi] + w2*e2w[wi] + shw[wi];
                    acc = fmaf(xr[xc], wv, acc);
                }
            }
        }
        out[(size_t)b*XIM + ((size_t)c*256 + y)*256 + xx] = acc;
    }
}

extern "C" void kernel_launch(void* const* d_in, const int* in_sizes, int n_in,
                              void* d_out, int out_size, void* d_ws, size_t ws_size,
                              hipStream_t stream){
    (void)in_sizes; (void)n_in; (void)out_size; (void)ws_size;
    const float* x   = (const float*)d_in[0];
    const float* gw  = (const float*)d_in[1];
    const float* gb  = (const float*)d_in[2];
    const float* ew  = (const float*)d_in[3];
    const float* ebv = (const float*)d_in[4];
    const float* sw  = (const float*)d_in[5];
    const float* sbv = (const float*)d_in[6];
    float* out = (float*)d_out;

    short* wt2   = (short*)d_ws;                          // 74240 f16 = 148480 B
    short* gwA   = wt2 + 74240;                           // 9216 f16 = 18432 B (end: 166912)
    int*   cnt   = (int*)((char*)d_ws + 166912);          // cnt[0]=flags, cnt[1]=reroutes
    int*   fixlist = cnt + 4;                             // MAXFIX ints (end: 166928+262144)
    int4*  fxroute = (int4*)((char*)d_ws + 429072);       // MAXFIX int4 (429072%16==0)

    prep_weights<<<dim3(326),  dim3(256), 0, stream>>>(ew, sw, ebv, sbv, gw, wt2, gwA, cnt);
    moe_main    <<<dim3(2048), dim3(512), 0, stream>>>(x, wt2, gwA, gb, out, cnt, fixlist);
    fixup_route <<<dim3(256),  dim3(256), 0, stream>>>(x, gw, gb, cnt, fixlist, fxroute);
    fixup_out   <<<dim3(128),  dim3(256), 0, stream>>>(x, ew, sw, ebv, sbv, cnt, fxroute, out);
}

// Round 22
// 212.247 us; speedup vs baseline: 1.9412x; 1.9412x over previous
//
#include <hip/hip_runtime.h>

typedef __attribute__((ext_vector_type(8)))  short bf16x8;   // 8 bf16 = 4 VGPR MFMA operand
typedef __attribute__((ext_vector_type(16))) float f32x16;   // 32x32 MFMA accumulator

#define XIM (32*256*256)

__device__ __forceinline__ short f2bf(float f){
    unsigned int u = __builtin_bit_cast(unsigned int, f);
    u += 0x7fffu + ((u >> 16) & 1u);           // RNE, no NaN inputs here
    return (short)(u >> 16);
}
__device__ __forceinline__ float bf2f(short s){
    unsigned int u = ((unsigned int)(unsigned short)s) << 16;
    return __builtin_bit_cast(float, u);
}
__device__ __forceinline__ void glds16(const short* g, short* l){
    __builtin_amdgcn_global_load_lds(
        (const __attribute__((address_space(1))) unsigned int*)g,
        (__attribute__((address_space(3))) unsigned int*)l,
        16, 0, 0);
}

// ---- prep: folded weights W'_e = W_e + W_s -> wt2[es8][tap9][cio4][cout32][8ci] bf16 (144KB);
//      biasmat[c32][k16] (k<8: eb+sb, else 0) ----
__global__ __launch_bounds__(256) void prep_weights(const float* __restrict__ ew,
                                                    const float* __restrict__ sw,
                                                    const float* __restrict__ ebv,
                                                    const float* __restrict__ sbv,
                                                    short* __restrict__ wt2){
    int i = blockIdx.x * 256 + threadIdx.x;      // 290 blocks * 256 = 74240 exactly
    if(i < 73728){
        int c7  = i & 7;
        int col = (i >> 3) & 31;                 // cout
        int cio = (i >> 8) & 3;                  // ci octet
        int rest = i >> 10;                      // 0..71
        int tap = rest % 9;
        int es  = rest / 9;                      // 0..7
        int ci  = cio*8 + c7;
        float v = ew[((es*32 + col)*32 + ci)*9 + tap] + sw[(col*32 + ci)*9 + tap];
        wt2[i] = f2bf(v);
    } else {                                     // biasmat
        int j = i - 73728, c = j >> 4, k = j & 15;
        float v = (k < 8) ? (ebv[k*32 + c] + sbv[c]) : 0.f;
        wt2[i] = f2bf(v);
    }
}

// ---- gate (r16-measured, 103us): dbuf 4-ci chunks; stage(cc+1) overlaps compute(cc);
//      1 barrier/chunk. 1024 blocks x 2 rows; fp32 conv -> top2 (fp64 on tight margin) ----
__global__ __launch_bounds__(256) void gate_kernel(const float* __restrict__ x,
                                                   const float* __restrict__ gw,
                                                   const float* __restrict__ gb,
                                                   short* __restrict__ route){
    __shared__ float xs[2][16][272];             // 2 bufs x [r4*4+cid][4+xx], 34.8 KB
    int raw = blockIdx.x;                        // 1024; XCD chunk swizzle (1024%8==0)
    int wg  = (raw & 7)*128 + (raw >> 3);
    int b   = wg >> 7;
    int y0  = (wg & 127) * 2;
    int t   = threadIdx.x;
    int wv  = t >> 6, lane = t & 63;
    const float* xim = x + (size_t)b * XIM;

    if(t < 64){                                  // edge zeros, both buffers; persist
        int bufi = t >> 5, s2 = (t >> 1) & 15;
        if(t & 1) xs[bufi][s2][260] = 0.f; else xs[bufi][s2][3] = 0.f;
    }

    auto STAGE = [&](int cc, int bufi){          // 16 segs over 4 waves, float4 per lane
        #pragma unroll
        for(int sg=0; sg<4; ++sg){
            int seg = wv*4 + sg;
            int r4  = seg >> 2, cid = seg & 3;   // staged rows y0-1 .. y0+2
            int ci  = cc*4 + cid;
            int yy  = y0 - 1 + r4;
            const float* xr = xim + ((size_t)ci*256 + yy)*256;
            float4 v = make_float4(0.f,0.f,0.f,0.f);
            if(yy >= 0 && yy < 256) v = *(const float4*)(xr + lane*4);
            *(float4*)(&xs[bufi][seg][4 + lane*4]) = v;
        }
    };

    float g[2][8];
    #pragma unroll
    for(int pr=0;pr<2;++pr)
        #pragma unroll
        for(int e=0;e<8;++e) g[pr][e] = 0.f;

    STAGE(0, 0);
    __syncthreads();                             // chunk0 + edge zeros visible
    for(int cc=0; cc<8; ++cc){                   // ci chunks of 4
        if(cc < 7) STAGE(cc+1, (cc+1)&1);        // prefetch overlaps compute below
        const int bufi = cc & 1;
        #pragma unroll
        for(int cid=0; cid<4; ++cid){
            float sv[4][3];
            #pragma unroll
            for(int r4=0;r4<4;++r4){
                sv[r4][0] = xs[bufi][r4*4+cid][t+3];   // xx = t-1+kw -> idx xx+4 = t+3+kw
                sv[r4][1] = xs[bufi][r4*4+cid][t+4];
                sv[r4][2] = xs[bufi][r4*4+cid][t+5];
            }
            const float* gwp = gw + (cc*4 + cid)*9;    // gw[e][ci][kh][kw], e-stride 288
            #pragma unroll
            for(int e=0;e<8;++e){
                #pragma unroll
                for(int kh=0;kh<3;++kh){
                    #pragma unroll
                    for(int kw=0;kw<3;++kw){
                        float wval = gwp[e*288 + kh*3 + kw];
                        g[0][e] = fmaf(sv[kh][kw],   wval, g[0][e]);
                        g[1][e] = fmaf(sv[kh+1][kw], wval, g[1][e]);
                    }
                }
            }
        }
        __syncthreads();                         // publish cc+1; reads of buf done before reuse
    }

    #pragma unroll
    for(int pr=0; pr<2; ++pr){
        float v1b=-1e30f, v2b=-1e30f, v3b=-1e30f, r1=0.f, r2=0.f; int i1=-1, i2=-1;
        #pragma unroll
        for(int e=0;e<8;e++){
            float se = 1.f/(1.f + expf(-g[pr][e]));
            float be = se + gb[e];
            if(be > v1b){ v3b=v2b; v2b=v1b; r2=r1; i2=i1; v1b=be; r1=se; i1=e; }
            else if(be > v2b){ v3b=v2b; v2b=be; r2=se; i2=e; }
            else if(be > v3b){ v3b=be; }
        }
        if(v2b - v3b < 2e-5f){                   // fp64 recompute (rare)
            int y = y0 + pr;
            double gd[8];
            #pragma unroll
            for(int e=0;e<8;e++) gd[e] = 0.0;
            for(int ci=0; ci<32; ++ci){
                for(int kh=0; kh<3; ++kh){
                    int yy = y + kh - 1;
                    if(yy < 0 || yy >= 256) continue;
                    const float* xr = xim + ((size_t)ci*256 + yy)*256;
                    for(int kw=0; kw<3; ++kw){
                        int xx = t + kw - 1;
                        if(xx < 0 || xx >= 256) continue;
                        double xv = (double)xr[xx];
                        const float* gwp = gw + ci*9 + kh*3 + kw;
                        #pragma unroll
                        for(int e=0;e<8;e++) gd[e] += xv * (double)gwp[e*288];
                    }
                }
            }
            double b1=-1e30, b2=-1e30; double rr1=0.0, rr2=0.0; int j1=-1, j2=-1;
            #pragma unroll
            for(int e=0;e<8;e++){
                double sd = 1.0/(1.0 + exp(-gd[e]));
                double bd = sd + (double)gb[e];
                if(bd > b1){ b2=b1; rr2=rr1; j2=j1; b1=bd; rr1=sd; j1=e; }
                else if(bd > b2){ b2=bd; rr2=sd; j2=e; }
            }
            i1=j1; i2=j2; r1=(float)rr1; r2=(float)rr2;
        }
        float m  = fmaxf(r1, r2);
        float e1 = expf(r1-m), e2 = expf(r2-m);
        float inv = 1.f/(e1+e2);
        float w1 = e1*inv, w2 = e2*inv;          // ROUTE_SCALE = 1
        bf16x8 ov;
        #pragma unroll
        for(int e=0;e<8;e++){
            float dv = (e==i1) ? w1 : ((e==i2) ? w2 : 0.f);
            ov[e] = f2bf(dv);
        }
        *(bf16x8*)(route + ((size_t)(b*256 + y0 + pr)*256 + t)*8) = ov;
    }
}

// ---- main (r17-measured, ~71us): weights-stationary 144KB/block; 2048 blocks x 512 thr;
//      8 waves x 1 row; b128-packed x staging. ----
__global__ __launch_bounds__(512, 2) void moe_main(const float* __restrict__ x,
                                                   const short* __restrict__ wt2,
                                                   const short* __restrict__ route,
                                                   float* __restrict__ out){
    __shared__ __align__(16) short wlds[73728];      // [es8][tap9][cio4][cout32][8ci], 144 KB
    __shared__ __align__(16) short xt[10*2*34*8];    // [row10][cic2][px34][8ci] one hf, 10.88 KB
    int raw = blockIdx.x;                            // 2048; XCD chunk swizzle
    int wg  = (raw & 7)*256 + (raw >> 3);
    int b   = wg >> 8;
    int y0  = ((wg >> 3) & 31) * 8;
    int x0  = (wg & 7) * 32;
    int t   = threadIdx.x;                           // 0..511
    int wv  = t >> 6, l = t & 63, col = l & 31, hi = l >> 5;

    // stage ALL folded weights once: 144 chunks of 1 KB over 8 waves, async
    #pragma unroll
    for(int j=0;j<18;++j){
        int c = wv + 8*j;
        glds16(wt2 + c*512 + l*8, wlds + c*512);
    }

    const float* xim = x + (size_t)b*XIM;
    int yy = y0 + wv;                                // this wave's output row
    bf16x8 biasA = *(const bf16x8*)(wt2 + 73728 + col*16 + hi*8);      // L2-hot
    bf16x8 rfrag = *(const bf16x8*)(route + ((size_t)(b*256 + yy)*256 + x0 + col)*8);

    // x tile: stage per ci-half into xt (b128-packed), cache B-frags in regs
    bf16x8 Bf[3][2][3];                              // [kh][hf][kw] = 72 VGPR
    #pragma unroll
    for(int hf=0; hf<2; ++hf){
        if(hf) __syncthreads();                      // hf0 Bf reads done before overwrite
        // rows y0-1..y0+8, ci = hf*16..+15, px x0-1..x0+32; 8ci packed -> ds_write_b128
        #pragma unroll
        for(int i=0;i<2;++i){
            int u = t + i*512;                       // 640 main units: [row10][cic2][px32]
            if(u < 640){
                int px = u & 31, rc = u >> 5;        // rc 0..19 = row*2+cic
                int row = rc >> 1, cic = rc & 1;
                int cib = hf*16 + cic*8;
                int ry = y0 - 1 + row, xx = x0 - 1 + px;
                bool ok = (ry>=0 && ry<256 && xx>=0 && xx<256);
                bf16x8 pk;
                #pragma unroll
                for(int j2=0;j2<8;++j2){
                    float v = ok ? xim[((size_t)(cib+j2)*256 + ry)*256 + xx] : 0.f;
                    pk[j2] = f2bf(v);
                }
                *(bf16x8*)(&xt[((row*2 + cic)*34 + px)*8]) = pk;
            }
        }
        if(t < 40){                                  // halo units: px 32,33
            int pxh = 32 + (t & 1), rc = t >> 1;     // rc 0..19
            int row = rc >> 1, cic = rc & 1;
            int cib = hf*16 + cic*8;
            int ry = y0 - 1 + row, xx = x0 - 1 + pxh;
            bool ok = (ry>=0 && ry<256 && xx>=0 && xx<256);
            bf16x8 pk;
            #pragma unroll
            for(int j2=0;j2<8;++j2){
                float v = ok ? xim[((size_t)(cib+j2)*256 + ry)*256 + xx] : 0.f;
                pk[j2] = f2bf(v);
            }
            *(bf16x8*)(&xt[((row*2 + cic)*34 + pxh)*8]) = pk;
        }
        __syncthreads();                             // xt(hf) staged; 1st also drains weight glds
        #pragma unroll
        for(int kh=0;kh<3;++kh)                      // wave rows wv..wv+2
            #pragma unroll
            for(int kw=0;kw<3;++kw)
                Bf[kh][hf][kw] = *(const bf16x8*)(&xt[(((wv+kh)*2 + hi)*34 + col + kw)*8]);
    }

    f32x16 z = {};
    f32x16 oa = __builtin_amdgcn_mfma_f32_32x32x16_bf16(biasA, rfrag, z, 0,0,0);

    #pragma unroll
    for(int es=0; es<8; ++es){                       // folded experts (shared absorbed)
        f32x16 acc = {};
        #pragma unroll
        for(int tap=0; tap<9; ++tap){
            const int kh = tap/3, kw = tap - kh*3;
            #pragma unroll
            for(int hf=0; hf<2; ++hf){
                bf16x8 a = *(const bf16x8*)(&wlds[(((es*9 + tap)*4 + hf*2 + hi)*32 + col)*8]);
                acc = __builtin_amdgcn_mfma_f32_32x32x16_bf16(a, Bf[kh][hf][kw], acc, 0,0,0);
            }
        }
        float d = bf2f(rfrag[es]);
        #pragma unroll
        for(int r=0;r<16;r++) oa[r] += d*acc[r];
    }

    float* ob = out + (size_t)b*XIM;
    #pragma unroll
    for(int r=0;r<16;r++){
        int c = hi*4 + (r&3) + 8*(r>>2);             // C/D: col=lane&31, row=(r&3)+8*(r>>2)+4*hi
        ob[((size_t)c*256 + yy)*256 + x0 + col] = oa[r];
    }
}

extern "C" void kernel_launch(void* const* d_in, const int* in_sizes, int n_in,
                              void* d_out, int out_size, void* d_ws, size_t ws_size,
                              hipStream_t stream){
    (void)in_sizes; (void)n_in; (void)out_size; (void)ws_size;
    const float* x   = (const float*)d_in[0];
    const float* gw  = (const float*)d_in[1];
    const float* gb  = (const float*)d_in[2];
    const float* ew  = (const float*)d_in[3];
    const float* ebv = (const float*)d_in[4];
    const float* sw  = (const float*)d_in[5];
    const float* sbv = (const float*)d_in[6];
    float* out = (float*)d_out;

    short* route = (short*)d_ws;                          // 524288 px * 8 bf16 = 8.39 MB
    short* wt2   = route + (size_t)8*256*256*8;           // 74240 bf16 (weights+bias)

    prep_weights<<<dim3(290),  dim3(256), 0, stream>>>(ew, sw, ebv, sbv, wt2);
    gate_kernel <<<dim3(1024), dim3(256), 0, stream>>>(x, gw, gb, route);
    moe_main    <<<dim3(2048), dim3(512), 0, stream>>>(x, wt2, route, out);
}